// Round 9
// baseline (590.296 us; speedup 1.0000x reference)
//
#include <hip/hip_runtime.h>
#include <hip/hip_bf16.h>
#include <stdint.h>

typedef __bf16 bf16x8 __attribute__((ext_vector_type(8)));
typedef float f32x4 __attribute__((ext_vector_type(4)));

// ---- ws element offsets (ushort) ----  (R1-proven layout)
#define WS_WIH 0          // [384][128]
#define WS_WHH 49152      // [384][128]
#define WS_HENC 98304     // [64][256]
#define WS_DEC 114688     // [16][128] rows 5..15 zero
#define WS_TOTAL 116736

// ---- LDS byte offsets ----
#define LDS_X  0          // [64][256B] bf16 swizzled; x=[E1|E2], later h_new
#define LDS_H  16384      // [64][256B] bf16 swizzled (h tile)
#define LDS_SZ 32768

__device__ __forceinline__ unsigned short f2bf(float f) {
    unsigned u = __float_as_uint(f);
    unsigned r = (u + 0x7FFFu + ((u >> 16) & 1u)) >> 16;   // RNE
    return (unsigned short)r;
}
__device__ __forceinline__ float bf2f(unsigned short u) {
    return __uint_as_float(((unsigned)u) << 16);
}

__device__ __forceinline__ unsigned cvt_pk_bf16(float a, float b) {
    unsigned r;
    asm("v_cvt_pk_bf16_f32 %0, %1, %2" : "=v"(r) : "v"(a), "v"(b));
    return r;
}

__device__ __forceinline__ float fast_rcp(float x) { return __builtin_amdgcn_rcpf(x); }
__device__ __forceinline__ float sigmf(float x) { return fast_rcp(1.0f + __expf(-x)); }
__device__ __forceinline__ float tanh_fast(float x) {
    float t = __expf(-2.0f * fabsf(x));
    float r = (1.0f - t) * fast_rcp(1.0f + t);
    return copysignf(r, x);
}

__global__ void convert_weights_kernel(const float* __restrict__ wih,
                                       const float* __restrict__ whh,
                                       const float* __restrict__ henc,
                                       const float* __restrict__ dec,
                                       unsigned short* __restrict__ ws) {
    int i = blockIdx.x * 256 + threadIdx.x;
    if (i >= WS_TOTAL) return;
    float v;
    if (i < WS_WHH)        v = wih[i];
    else if (i < WS_HENC)  v = whh[i - WS_WHH];
    else if (i < WS_DEC)   v = henc[i - WS_HENC];
    else { int d = i - WS_DEC; v = (d < 640) ? dec[d] : 0.0f; }
    ws[i] = f2bf(v);
}

// ================= Fused kernel: 64 rows/block, 8 waves =================
// Wave w: E2 sub-tile (nt=w&3, 2 mt), gate j-tile [16w,16w+16) with register
// double-buffered weight prefetch (breaks the serial B-frag L2 chains).
__launch_bounds__(512, 2)
__global__ void fused_rnn_kernel(const float* __restrict__ pos,
                                 const float* __restrict__ h_other,
                                 const float* __restrict__ h,
                                 const float* __restrict__ enc_W,
                                 const float* __restrict__ enc_b,
                                 const float* __restrict__ henc_b,
                                 const float* __restrict__ b_ih,
                                 const float* __restrict__ b_hh,
                                 const float* __restrict__ dec_b,
                                 const unsigned short* __restrict__ ws,
                                 float* __restrict__ out,
                                 float* __restrict__ hnew,
                                 int N) {
    __shared__ char sm[LDS_SZ];
    const int tid = threadIdx.x;
    const int w   = tid >> 6;      // wave 0..7
    const int l   = tid & 63;
    const int lg  = l >> 4;
    const int ln  = l & 15;
    const int row0 = blockIdx.x * 64;

    // ---- issue E2 B-frag loads first (L2; independent of everything) ----
    const int nt = w & 3;          // E2 col tile
    bf16x8 Bh[8];
    {
        const unsigned short* hb = ws + WS_HENC + (size_t)(16 * nt + ln) * 256;
        #pragma unroll
        for (int ks = 0; ks < 8; ++ks)
            Bh[ks] = *reinterpret_cast<const bf16x8*>(hb + ks * 32 + lg * 8);
    }

    // ---------------- stage h -> LDS_H, E1 -> LDS_X cols 0..63 ----------------
    #pragma unroll
    for (int j = 0; j < 4; ++j) {
        int e0  = (tid + 512 * j) * 4;
        int row = e0 >> 7;
        int col = e0 & 127;
        int grow = row0 + row; if (grow > N - 1) grow = N - 1;
        float4 v = *reinterpret_cast<const float4*>(h + (size_t)grow * 128 + col);
        uint2 p;
        p.x = cvt_pk_bf16(v.x, v.y);
        p.y = cvt_pk_bf16(v.z, v.w);
        int boff = LDS_H + row * 256 + ((col * 2) ^ ((row & 7) << 4));
        *reinterpret_cast<uint2*>(sm + boff) = p;
    }
    {
        int row = tid >> 3;
        int c0  = (tid & 7) * 8;
        int grow = row0 + row; if (grow > N - 1) grow = N - 1;
        float p0 = pos[(size_t)grow * 2 + 0];
        float p1 = pos[(size_t)grow * 2 + 1];
        #pragma unroll
        for (int q = 0; q < 4; ++q) {
            int c = c0 + q * 2;
            float v0 = fmaxf(p0 * enc_W[c * 2]     + p1 * enc_W[c * 2 + 1] + enc_b[c], 0.f);
            float v1 = fmaxf(p0 * enc_W[c * 2 + 2] + p1 * enc_W[c * 2 + 3] + enc_b[c + 1], 0.f);
            unsigned pk = cvt_pk_bf16(v0, v1);
            int boff = LDS_X + row * 256 + ((c * 2) ^ ((row & 7) << 4));
            *reinterpret_cast<unsigned*>(sm + boff) = pk;
        }
    }

    // ---------------- E2 = relu(h_other @ henc_W.T + b) -> LDS_X cols 64..127 ----------------
    // wave w: cols [16nt,16nt+16), rows mt = (w>>2)*2 + {0,1}; A direct from global f32.
    {
        f32x4 e2[2];
        #pragma unroll
        for (int m2 = 0; m2 < 2; ++m2) e2[m2] = (f32x4){0.f, 0.f, 0.f, 0.f};
        #pragma unroll
        for (int m2 = 0; m2 < 2; ++m2) {
            int mt = (w >> 2) * 2 + m2;
            int grow = row0 + 16 * mt + ln; if (grow > N - 1) grow = N - 1;
            const float* rp = h_other + (size_t)grow * 256 + lg * 8;
            float4 hb0[8], hb1[8];
            #pragma unroll
            for (int ks = 0; ks < 8; ++ks) {
                hb0[ks] = *reinterpret_cast<const float4*>(rp + ks * 32);
                hb1[ks] = *reinterpret_cast<const float4*>(rp + ks * 32 + 4);
            }
            #pragma unroll
            for (int ks = 0; ks < 8; ++ks) {
                union { unsigned u[4]; bf16x8 b; } af;
                af.u[0] = cvt_pk_bf16(hb0[ks].x, hb0[ks].y);
                af.u[1] = cvt_pk_bf16(hb0[ks].z, hb0[ks].w);
                af.u[2] = cvt_pk_bf16(hb1[ks].x, hb1[ks].y);
                af.u[3] = cvt_pk_bf16(hb1[ks].z, hb1[ks].w);
                e2[m2] = __builtin_amdgcn_mfma_f32_16x16x32_bf16(af.b, Bh[ks], e2[m2], 0, 0, 0);
            }
        }
        int col = 16 * nt + ln;
        float bias = henc_b[col];
        #pragma unroll
        for (int m2 = 0; m2 < 2; ++m2) {
            int mt = (w >> 2) * 2 + m2;
            #pragma unroll
            for (int i = 0; i < 4; ++i) {
                int row = 16 * mt + lg * 4 + i;
                float v = fmaxf(e2[m2][i] + bias, 0.f);
                *reinterpret_cast<unsigned short*>(
                    sm + LDS_X + row * 256 + (((64 + col) * 2) ^ ((row & 7) << 4))) = f2bf(v);
            }
        }
    }

    // ---- gate prologue: t=0 weights + epilogue biases (issue before barrier) ----
    const unsigned short* WIH = ws + WS_WIH;
    const unsigned short* WHH = ws + WS_WHH;
    const int jrow = 16 * w + ln;     // this wave's j index per lane

    #define LOADW(d0, d1, d2, Wp, kk) { \
        d0 = *reinterpret_cast<const bf16x8*>((Wp) + (size_t)(jrow) * 128 + (kk)); \
        d1 = *reinterpret_cast<const bf16x8*>((Wp) + (size_t)(128 + jrow) * 128 + (kk)); \
        d2 = *reinterpret_cast<const bf16x8*>((Wp) + (size_t)(256 + jrow) * 128 + (kk)); }

    bf16x8 Ba0, Ba1, Ba2, Bb0, Bb1, Bb2;
    LOADW(Ba0, Ba1, Ba2, WIH, lg * 8);
    float br  = b_ih[jrow] + b_hh[jrow];
    float bz  = b_ih[128 + jrow] + b_hh[128 + jrow];
    float bxn = b_ih[256 + jrow];
    float bhn = b_hh[256 + jrow];

    __syncthreads();   // barrier 1: X (E1+E2) and H complete

    // ---------------- gates: wave w -> j-tile [16w,16w+16) x 64 rows ----------------
    // acc[mt][0]=r, [1]=z, [2]=xn, [3]=hn
    f32x4 acc[4][4];
    #pragma unroll
    for (int a = 0; a < 4; ++a)
        #pragma unroll
        for (int b = 0; b < 4; ++b) acc[a][b] = (f32x4){0.f, 0.f, 0.f, 0.f};

    #define GSTEP(t, C0, C1, C2, N0, N1, N2) { \
        if ((t) < 7) { \
            const unsigned short* Wp = (((t) + 1) < 4) ? WIH : WHH; \
            const int kkn = ((((t) + 1) & 3) * 32) + lg * 8; \
            LOADW(N0, N1, N2, Wp, kkn); \
        } \
        const int abase = ((t) < 4) ? LDS_X : LDS_H; \
        const int kb = ((t) & 3) * 64; \
        bf16x8 Af[4]; \
        _Pragma("unroll") \
        for (int mt = 0; mt < 4; ++mt) { \
            int row = 16 * mt + ln; \
            Af[mt] = *reinterpret_cast<const bf16x8*>( \
                sm + abase + row * 256 + ((kb + lg * 16) ^ ((row & 7) << 4))); \
        } \
        const int nj = ((t) < 4) ? 2 : 3; \
        _Pragma("unroll") \
        for (int mt = 0; mt < 4; ++mt) { \
            acc[mt][0]  = __builtin_amdgcn_mfma_f32_16x16x32_bf16(Af[mt], C0, acc[mt][0], 0, 0, 0); \
            acc[mt][1]  = __builtin_amdgcn_mfma_f32_16x16x32_bf16(Af[mt], C1, acc[mt][1], 0, 0, 0); \
            acc[mt][nj] = __builtin_amdgcn_mfma_f32_16x16x32_bf16(Af[mt], C2, acc[mt][nj], 0, 0, 0); \
        } }

    GSTEP(0, Ba0, Ba1, Ba2, Bb0, Bb1, Bb2);
    GSTEP(1, Bb0, Bb1, Bb2, Ba0, Ba1, Ba2);
    GSTEP(2, Ba0, Ba1, Ba2, Bb0, Bb1, Bb2);
    GSTEP(3, Bb0, Bb1, Bb2, Ba0, Ba1, Ba2);
    GSTEP(4, Ba0, Ba1, Ba2, Bb0, Bb1, Bb2);
    GSTEP(5, Bb0, Bb1, Bb2, Ba0, Ba1, Ba2);
    GSTEP(6, Ba0, Ba1, Ba2, Bb0, Bb1, Bb2);
    GSTEP(7, Bb0, Bb1, Bb2, Ba0, Ba1, Ba2);
    #undef GSTEP
    #undef LOADW

    __syncthreads();   // barrier 2: gate reads of X/H done before X overwrite

    // ---------------- GRU epilogue (j = 16w+ln; h from LDS bf16) ----------------
    #pragma unroll
    for (int mt = 0; mt < 4; ++mt)
        #pragma unroll
        for (int i = 0; i < 4; ++i) {
            int row = mt * 16 + lg * 4 + i;
            int grow = row0 + row;
            float r  = sigmf(acc[mt][0][i] + br);
            float z  = sigmf(acc[mt][1][i] + bz);
            float xn = acc[mt][2][i] + bxn;
            float hn = acc[mt][3][i] + bhn;
            float nn = tanh_fast(xn + r * hn);
            unsigned short hu = *reinterpret_cast<const unsigned short*>(
                sm + LDS_H + row * 256 + ((jrow * 2) ^ ((row & 7) << 4)));
            float hp = bf2f(hu);
            float hv = (1.0f - z) * nn + z * hp;
            if (grow < N) hnew[(size_t)grow * 128 + jrow] = hv;
            *reinterpret_cast<unsigned short*>(
                sm + LDS_X + row * 256 + ((jrow * 2) ^ ((row & 7) << 4))) = f2bf(hv);
        }
    __syncthreads();   // barrier 3: h_new tile complete

    // ---------------- decoder: out = h_new @ dec_W.T + dec_b (waves 0..3) ----------------
    if (w < 4) {
        bf16x8 dbf[4];
        #pragma unroll
        for (int ks = 0; ks < 4; ++ks)
            dbf[ks] = *reinterpret_cast<const bf16x8*>(ws + WS_DEC + ln * 128 + ks * 32 + lg * 8);
        f32x4 oc = (f32x4){0.f, 0.f, 0.f, 0.f};
        #pragma unroll
        for (int ks = 0; ks < 4; ++ks) {
            int row = 16 * w + ln;
            bf16x8 af = *reinterpret_cast<const bf16x8*>(
                sm + LDS_X + row * 256 + ((ks * 64 + lg * 16) ^ ((row & 7) << 4)));
            oc = __builtin_amdgcn_mfma_f32_16x16x32_bf16(af, dbf[ks], oc, 0, 0, 0);
        }
        if (ln < 5) {
            float bias = dec_b[ln];
            #pragma unroll
            for (int i = 0; i < 4; ++i) {
                int grow = row0 + 16 * w + lg * 4 + i;
                if (grow < N) out[(size_t)grow * 5 + ln] = oc[i] + bias;
            }
        }
    }
}

extern "C" void kernel_launch(void* const* d_in, const int* in_sizes, int n_in,
                              void* d_out, int out_size, void* d_ws, size_t ws_size,
                              hipStream_t stream) {
    const float* pos     = (const float*)d_in[0];
    const float* h_other = (const float*)d_in[1];
    const float* h       = (const float*)d_in[2];
    const float* enc_W   = (const float*)d_in[3];
    const float* enc_b   = (const float*)d_in[4];
    const float* henc_W  = (const float*)d_in[5];
    const float* henc_b  = (const float*)d_in[6];
    const float* W_ih    = (const float*)d_in[7];
    const float* b_ih    = (const float*)d_in[8];
    const float* W_hh    = (const float*)d_in[9];
    const float* b_hh    = (const float*)d_in[10];
    const float* dec_W   = (const float*)d_in[11];
    const float* dec_b   = (const float*)d_in[12];

    int N = in_sizes[0] / 2;
    unsigned short* ws = (unsigned short*)d_ws;
    float* out  = (float*)d_out;
    float* hnew = out + (size_t)N * 5;

    hipLaunchKernelGGL(convert_weights_kernel, dim3((WS_TOTAL + 255) / 256), dim3(256), 0, stream,
                       W_ih, W_hh, henc_W, dec_W, ws);
    int blocks = (N + 63) / 64;
    hipLaunchKernelGGL(fused_rnn_kernel, dim3(blocks), dim3(512), 0, stream,
                       pos, h_other, h, enc_W, enc_b, henc_b, b_ih, b_hh, dec_b,
                       ws, out, hnew, N);
}